// Round 5
// baseline (112.768 us; speedup 1.0000x reference)
//
#include <hip/hip_runtime.h>
#include <hip/hip_bf16.h>
#include <math.h>

#define B_ROWS 4096
#define N_ROWS 8192
#define D 128
#define NCC 4              // column chunks of 2048 cols
#define K2 2.8853900818f   // 2*log2(e): exp(2c) = 2^(c*K2)

#define CHUNK_STRIDE 1088  // 1024 B (4 rows) + 64 B pad -> 2-way (free) LDS banks
#define BUF_BYTES (32 * CHUNK_STRIDE)

typedef __attribute__((ext_vector_type(8))) short bf16x8;
typedef __attribute__((ext_vector_type(4))) float f32x4;

#if __has_builtin(__builtin_amdgcn_exp2f)
#define EXP2(x) __builtin_amdgcn_exp2f(x)
#else
#define EXP2(x) exp2f(x)
#endif

__device__ __forceinline__ void async_copy_1k(void* lds_dst, const void* g_src_lane) {
  __builtin_amdgcn_global_load_lds(
      (const __attribute__((address_space(1))) void*)g_src_lane,
      (__attribute__((address_space(3))) void*)lds_dst, 16, 0, 0);
}

// ---- Kernel 1: normalize pair (r, r+B); exact fp32 positive; zero cnt/out ----
__global__ __launch_bounds__(256) void normalize_pos_kernel(
    const float* __restrict__ z_i, const float* __restrict__ z_j,
    ushort* __restrict__ Z, float* __restrict__ pos_buf,
    int* __restrict__ cnt, float* __restrict__ out) {
  if (blockIdx.x == 0) {
    if (threadIdx.x < 64) cnt[threadIdx.x] = 0;
    if (threadIdx.x == 64) out[0] = 0.f;
  }
  const int wave = threadIdx.x >> 6;
  const int lane = threadIdx.x & 63;
  const int r = blockIdx.x * 4 + wave;
  float2 vi = *(const float2*)(z_i + (size_t)r * D + lane * 2);
  float2 vj = *(const float2*)(z_j + (size_t)r * D + lane * 2);
  float ssi = vi.x * vi.x + vi.y * vi.y;
  float ssj = vj.x * vj.x + vj.y * vj.y;
  float cr = vi.x * vj.x + vi.y * vj.y;
#pragma unroll
  for (int off = 32; off > 0; off >>= 1) {
    ssi += __shfl_xor(ssi, off);
    ssj += __shfl_xor(ssj, off);
    cr += __shfl_xor(cr, off);
  }
  float si = 1.0f / fmaxf(sqrtf(ssi), 1e-12f);
  float sj = 1.0f / fmaxf(sqrtf(ssj), 1e-12f);
  __hip_bfloat16 a0 = __float2bfloat16(vi.x * si);
  __hip_bfloat16 a1 = __float2bfloat16(vi.y * si);
  __hip_bfloat16 b0 = __float2bfloat16(vj.x * sj);
  __hip_bfloat16 b1 = __float2bfloat16(vj.y * sj);
  ushort2 oi, oj;
  oi.x = *(ushort*)&a0; oi.y = *(ushort*)&a1;
  oj.x = *(ushort*)&b0; oj.y = *(ushort*)&b1;
  *(ushort2*)(Z + (size_t)r * D + lane * 2) = oi;
  *(ushort2*)(Z + (size_t)(r + B_ROWS) * D + lane * 2) = oj;
  if (lane == 0) {
    float pos = 2.0f * cr * si * sj;
    pos_buf[r] = pos;
    pos_buf[r + B_ROWS] = pos;
  }
}

// ---- Kernel 2: streaming exp-rowsum GEMM + fused finalize ----
// Block (cc, rb): rows [rb*128, +128), cols [cc*2048, +2048) as 16 B-tiles.
// A panel register-resident; B double-buffered via global_load_lds;
// row-sums in registers across all 16 tiles. Last block of each rb
// (completion counter) computes log-terms and atomically adds to out.
__global__ __launch_bounds__(256, 2) void sim_kernel(
    const ushort* __restrict__ Z, const float* __restrict__ pos_buf,
    float* __restrict__ partials, int* __restrict__ cnt,
    float* __restrict__ out) {
  __shared__ __align__(16) char Bs[2 * BUF_BYTES];
  __shared__ float rowled[128];
  __shared__ float wsum[4];
  __shared__ int done_flag;

  const int cc = blockIdx.x;  // 0..3
  const int rb = blockIdx.y;  // 0..63
  const int t = threadIdx.x;
  const int lane = t & 63;
  const int w = t >> 6;
  const int wy = w >> 1, wx = w & 1;
  const int l15 = lane & 15;
  const int l4 = lane >> 4;  // 0..3
  const int diag_it = (cc == (rb >> 4)) ? (rb & 15) : -1;

  // A fragments: 64 rows for this wave's row-half, resident all kernel.
  bf16x8 a[4][4];
  {
    const int arow = rb * 128 + wy * 64 + l15;
#pragma unroll
    for (int rs = 0; rs < 4; ++rs)
#pragma unroll
      for (int ks = 0; ks < 4; ++ks)
        a[rs][ks] = *(const bf16x8*)(Z + (size_t)(arow + rs * 16) * D + ks * 32 + l4 * 8);
  }

  float rowacc[4][4];
#pragma unroll
  for (int rs = 0; rs < 4; ++rs)
#pragma unroll
    for (int r = 0; r < 4; ++r) rowacc[rs][r] = 0.f;

  // stage tile 0 into buffer 0
  {
    const char* gbase = (const char*)Z + (size_t)(cc * 16) * 128 * 256;
#pragma unroll
    for (int q = 0; q < 8; ++q) {
      const int c = w * 8 + q;
      async_copy_1k(Bs + c * CHUNK_STRIDE, gbase + c * 1024 + lane * 16);
    }
  }

  // B-fragment base: tile-row = wx*64 + cs*16 + l15, k-offset l4*16 (+ks*64)
  const int bfrag_base = (wx * 16 + (l15 >> 2)) * CHUNK_STRIDE + (l15 & 3) * 256 + l4 * 16;

  for (int it = 0; it < 16; ++it) {
    __syncthreads();  // drains in-flight glds: buf[it&1] ready, prev reads done
    if (it + 1 < 16) {
      const char* gbase = (const char*)Z + (size_t)(cc * 16 + it + 1) * 128 * 256;
      char* dbase = Bs + ((it + 1) & 1) * BUF_BYTES;
#pragma unroll
      for (int q = 0; q < 8; ++q) {
        const int c = w * 8 + q;
        async_copy_1k(dbase + c * CHUNK_STRIDE, gbase + c * 1024 + lane * 16);
      }
    }
    const char* bbuf = Bs + (it & 1) * BUF_BYTES;
    const bool isdiag = (it == diag_it);

#pragma unroll
    for (int cs = 0; cs < 4; ++cs) {
      bf16x8 b[4];
#pragma unroll
      for (int ks = 0; ks < 4; ++ks)
        b[ks] = *(const bf16x8*)(bbuf + bfrag_base + cs * (4 * CHUNK_STRIDE) + ks * 64);

      f32x4 c4[4];
#pragma unroll
      for (int rs = 0; rs < 4; ++rs) c4[rs] = (f32x4){0.f, 0.f, 0.f, 0.f};
#pragma unroll
      for (int ks = 0; ks < 4; ++ks)
#pragma unroll
        for (int rs = 0; rs < 4; ++rs)
          c4[rs] = __builtin_amdgcn_mfma_f32_16x16x32_bf16(a[rs][ks], b[ks], c4[rs], 0, 0, 0);

      if (isdiag) {
        const int colInT = wx * 64 + cs * 16 + l15;
#pragma unroll
        for (int rs = 0; rs < 4; ++rs) {
          const int rowBase = wy * 64 + rs * 16 + l4 * 4;
#pragma unroll
          for (int reg = 0; reg < 4; ++reg) {
            float e = EXP2(c4[rs][reg] * K2);
            rowacc[rs][reg] += (rowBase + reg != colInT) ? e : 0.f;
          }
        }
      } else {
#pragma unroll
        for (int rs = 0; rs < 4; ++rs)
#pragma unroll
          for (int reg = 0; reg < 4; ++reg)
            rowacc[rs][reg] += EXP2(c4[rs][reg] * K2);
      }
    }
  }

  // reduce rowacc across the 16 column-lanes (low 4 lane bits)
#pragma unroll
  for (int rs = 0; rs < 4; ++rs)
#pragma unroll
    for (int r = 0; r < 4; ++r) {
      float v = rowacc[rs][r];
      v += __shfl_xor(v, 1);
      v += __shfl_xor(v, 2);
      v += __shfl_xor(v, 4);
      v += __shfl_xor(v, 8);
      rowacc[rs][r] = v;
    }

  // combine the wx pair via LDS
  __syncthreads();  // retire last tile's LDS reads before reusing rowled
  if (wx == 0 && l15 == 0) {
#pragma unroll
    for (int rs = 0; rs < 4; ++rs)
#pragma unroll
      for (int r = 0; r < 4; ++r)
        rowled[wy * 64 + rs * 16 + l4 * 4 + r] = rowacc[rs][r];
  }
  __syncthreads();
  if (wx == 1 && l15 == 0) {
#pragma unroll
    for (int rs = 0; rs < 4; ++rs)
#pragma unroll
      for (int r = 0; r < 4; ++r)
        rowled[wy * 64 + rs * 16 + l4 * 4 + r] += rowacc[rs][r];
  }
  __syncthreads();

  if (t < 128)
    partials[(size_t)cc * N_ROWS + rb * 128 + t] = rowled[t];

  // completion: last block of this rb finalizes its 128 rows
  __threadfence();
  if (t == 0) done_flag = (atomicAdd(&cnt[rb], 1) == NCC - 1) ? 1 : 0;
  __syncthreads();
  if (done_flag) {
    __threadfence();  // acquire: other chunks' partials now visible
    float term = 0.f;
    if (t < 128) {
      const int row = rb * 128 + t;
      float tot = partials[row] + partials[N_ROWS + row] +
                  partials[2 * N_ROWS + row] + partials[3 * N_ROWS + row];
      term = __logf(tot) - pos_buf[row];
    }
#pragma unroll
    for (int off = 32; off > 0; off >>= 1) term += __shfl_xor(term, off);
    if (lane == 0) wsum[w] = term;
    __syncthreads();
    if (t == 0)
      atomicAdd(out, (wsum[0] + wsum[1] + wsum[2] + wsum[3]) * (1.0f / N_ROWS));
  }
}

extern "C" void kernel_launch(void* const* d_in, const int* in_sizes, int n_in,
                              void* d_out, int out_size, void* d_ws, size_t ws_size,
                              hipStream_t stream) {
  const float* z_i = (const float*)d_in[0];
  const float* z_j = (const float*)d_in[1];
  float* out = (float*)d_out;

  ushort* Z = (ushort*)d_ws;                                        // 2 MB
  float* partials = (float*)((char*)d_ws + (size_t)N_ROWS * D * 2); // 128 KB
  float* pos_buf = partials + (size_t)NCC * N_ROWS;                 // 32 KB
  int* cnt = (int*)(pos_buf + N_ROWS);                              // 256 B

  hipLaunchKernelGGL(normalize_pos_kernel, dim3(B_ROWS / 4), dim3(256), 0,
                     stream, z_i, z_j, Z, pos_buf, cnt, out);
  hipLaunchKernelGGL(sim_kernel, dim3(NCC, N_ROWS / 128), dim3(256), 0, stream,
                     Z, pos_buf, partials, cnt, out);
}